// Round 7
// baseline (639.699 us; speedup 1.0000x reference)
//
#include <hip/hip_runtime.h>

// Problem constants (fixed by setup_inputs): C=64, H*W=N=1048576, NUM_SP=2048.
#define NUM_SP 2048
#define NG_SUM 11         // sum groups: 10x 6-channel + 1x 4-channel (with count field)
#define SUM_THREADS 1024
#define SUM_CHUNKS 46     // 46*11 = 506 blocks ~ 2/CU
#define BCAST_THREADS 256
#define BCAST_CHUNKS 64   // grid (64, 16): 1024 blocks, 32KB LDS -> 4-5 blocks/CU
#define NGB 4             // bcast channels per block
#define FBITS 21
#define FMASK ((1ULL << FBITS) - 1ULL)
#define CNT_SHIFT 42      // count lives in field 2 of word 1 of the tail group

// DIAGNOSTIC ROUND: sum repeated 2x (doubles sums AND counts -> means exact),
// bcast repeated 4x (idempotent re-stores). Purpose: both kernels exceed the
// ~165us poison fills and surface in top-5 WITH counters. Wall cost ~+250us,
// information: true per-kernel durations + PMC, after 3 neutral rounds.
#define SUM_REP 2
#define BCAST_REP 4

// MODEL LEDGER:
//  Serial wall model fits r0-r6 within 3us: wall = fills(330us, ws poison 2x
//  1.07GB, same stream, precede us) + user_kernels.
//  => r1/r2/r4/r6 kernels total ~164us. Component split UNKNOWN (contradictory
//  models: r0->r1 64->32 DS ops scaled 2x; r1->r2 32->22 ops neutral; r6's
//  paired loads + bcast occupancy neutral). This round measures S=sum, B=bcast
//  directly. Decision tree in journal: (1) S~115,B~45 -> cut DS ops (16-bit
//  fields) or L2 atomics; (2) S<=90 -> trim mean/cnt/gaps; (3) B>=70 ->
//  restructure bcast.
// Fixed-point: field = round((v+6)*scale), 3 fields/u64, bias removed via
//  global per-seg count. scale=1024 (DIAG x2): max field 2*70*11981=1.68M <
//  2^21 (20% margin). Quant err on mean ~1.2e-5 << 4.9e-4 observed absmax.
//  Fallback scale=128: doubled whole-N count <=1250 -> 1.87M < 2^21.

__global__ __launch_bounds__(256) void zero_kernel(float* ws, int n) {
    int i = blockIdx.x * 256 + threadIdx.x;
    int stride = gridDim.x * 256;
    for (; i < n; i += stride) ws[i] = 0.0f;
}

// Paired-pixel loop: lanes process pixels (2i, 2i+1) via float2/int2 loads.
template <int CHN, bool WCNT, int THREADS>
__device__ __forceinline__ void sum_body_pair(const float* __restrict__ xg,
                                              const int* __restrict__ sp,
                                              unsigned long long* __restrict__ acc,
                                              int base, int end, int N,
                                              float scale, float bsr) {
    const int2* sp2 = (const int2*)sp;
    const int i0 = base >> 1;
    const int i1 = (end - base) >= 2 ? ((base + ((end - base) & ~1)) >> 1) : i0;
    for (int i = i0 + (int)threadIdx.x; i < i1; i += THREADS) {
        int2 ss = sp2[i];
        float2 v[CHN];
#pragma unroll
        for (int c = 0; c < CHN; ++c)
            v[c] = ((const float2*)(xg + (size_t)c * N))[i];
        unsigned long long qa0 = 0, qa1 = 0, qb0 = 0, qb1 = 0;
#pragma unroll
        for (int c = 0; c < CHN; ++c) {
            unsigned long long ua = (unsigned int)fmaf(v[c].x, scale, bsr);
            unsigned long long ub = (unsigned int)fmaf(v[c].y, scale, bsr);
            if (c < 3) { qa0 |= ua << (c * FBITS); qb0 |= ub << (c * FBITS); }
            else       { qa1 |= ua << ((c - 3) * FBITS); qb1 |= ub << ((c - 3) * FBITS); }
        }
        if (WCNT) { qa1 |= (1ULL << CNT_SHIFT); qb1 |= (1ULL << CNT_SHIFT); }
        atomicAdd(&acc[(ss.x << 1) + 0], qa0);
        atomicAdd(&acc[(ss.x << 1) + 1], qa1);
        atomicAdd(&acc[(ss.y << 1) + 0], qb0);
        atomicAdd(&acc[(ss.y << 1) + 1], qb1);
    }
    // odd tail (empty for even chunk sizes; thread 0 handles <=1 pixel)
    int tail = base + ((end - base) & ~1);
    if (threadIdx.x == 0) {
        for (int p = tail; p < end; ++p) {
            int s = sp[p];
            unsigned long long q0 = 0, q1 = 0;
#pragma unroll
            for (int c = 0; c < CHN; ++c) {
                unsigned long long u = (unsigned int)fmaf(xg[(size_t)c * N + p], scale, bsr);
                if (c < 3) q0 |= u << (c * FBITS);
                else       q1 |= u << ((c - 3) * FBITS);
            }
            if (WCNT) q1 |= (1ULL << CNT_SHIFT);
            atomicAdd(&acc[(s << 1) + 0], q0);
            atomicAdd(&acc[(s << 1) + 1], q1);
        }
    }
}

// Segment sums, privatized in LDS as 3x21-bit-field u64 fixed point.
// DIAG: body executed SUM_REP times (sums & counts scale together -> exact).
__global__ __launch_bounds__(SUM_THREADS, 8) void sum_kernel(
        const float* __restrict__ x, const int* __restrict__ sp,
        unsigned long long* __restrict__ outq,  // [chunk][g][s][2] (fallback: [g][s][2])
        int N, int chunks, int use_partials, float scale, float bsr) {
    __shared__ unsigned long long acc[NUM_SP * 2];
    for (int i = threadIdx.x; i < NUM_SP * 2; i += SUM_THREADS) acc[i] = 0ULL;
    __syncthreads();
    const int gs = blockIdx.y;
    const int chunk = blockIdx.x;
    int per = (N + chunks - 1) / chunks;
    per = (per + 1) & ~1;                  // even chunk base -> aligned float2
    const int base = chunk * per;
    int end = base + per; if (end > N) end = N;
    if (end > base) {
        const float* xg = x + (size_t)gs * 6 * N;
        for (int rep = 0; rep < SUM_REP; ++rep) {
            if (gs == NG_SUM - 1)
                sum_body_pair<4, true,  SUM_THREADS>(xg, sp, acc, base, end, N, scale, bsr);
            else
                sum_body_pair<6, false, SUM_THREADS>(xg, sp, acc, base, end, N, scale, bsr);
        }
    }
    __syncthreads();
    unsigned long long* dst = outq + (size_t)(use_partials ? (chunk * NG_SUM + gs) : gs)
                                     * (NUM_SP * 2);
    for (int i = threadIdx.x; i < NUM_SP * 2; i += SUM_THREADS) {
        unsigned long long v = acc[i];
        if (use_partials) dst[i] = v;
        else if (v) atomicAdd(&dst[i], v);
    }
}

// Extract per-segment pixel counts (x SUM_REP) from the tail group's count field.
__global__ __launch_bounds__(256) void cnt_kernel(const unsigned long long* __restrict__ partq,
                                                  float* __restrict__ counts, int chunks) {
    int s = blockIdx.x * 256 + threadIdx.x;
    if (s >= NUM_SP) return;
    unsigned long long c = 0;
    for (int k = 0; k < chunks; ++k)
        c += partq[(size_t)(k * NG_SUM + (NG_SUM - 1)) * (NUM_SP * 2) + (s << 1) + 1]
             >> CNT_SHIFT;
    counts[s] = (float)c;
}

// Reduce field partials over chunks, unbias, divide by (repeated) counts.
// mean = (fs - 6*scale*cnt)/scale / cnt with fs,cnt both x SUM_REP -> exact.
// Output layout: 4-channel float4 planes: means[((c>>2)*NUM_SP + s)*4 + (c&3)]
__global__ __launch_bounds__(256) void mean_kernel(const unsigned long long* __restrict__ partq,
                                                   const float* __restrict__ counts,
                                                   float* __restrict__ means,
                                                   int SC, int chunks, float scale) {
    int i = blockIdx.x * 256 + threadIdx.x;
    if (i >= SC) return;
    int s = i & (NUM_SP - 1);
    int c = i >> 11;
    int gs = c / 6;                       // 60..63 -> 10 (4-channel tail group)
    int f = c - gs * 6;
    int j = f / 3, sub = f - j * 3;
    unsigned long long fs = 0;
    for (int k = 0; k < chunks; ++k) {
        unsigned long long q = partq[(size_t)(k * NG_SUM + gs) * (NUM_SP * 2) + (s << 1) + j];
        fs += (q >> (sub * FBITS)) & FMASK;
    }
    float cnt = counts[s];
    double sv = ((double)fs - (double)cnt * (double)(6.0f * scale)) / (double)scale;
    means[((size_t)(c >> 2) * NUM_SP + s) * 4 + (c & 3)] = (float)(sv / fmax((double)cnt, 1.0));
}

// Broadcast: block (k,g) stages 4 channels' means (32 KB LDS), per QUAD of
// pixels: 1 int4 sp load + 4 LDS float4 reads + 4 coalesced float4 stores.
// DIAG: pixel loop repeated BCAST_REP times (idempotent re-stores).
__global__ __launch_bounds__(BCAST_THREADS, 5) void bcast_kernel(
        const int* __restrict__ sp, const float4* __restrict__ means4,
        float* __restrict__ out, int N) {
    __shared__ float4 tbl[NUM_SP];        // 32 KB
    const int g = blockIdx.y;
    for (int e = threadIdx.x; e < NUM_SP; e += BCAST_THREADS)
        tbl[e] = means4[(size_t)g * NUM_SP + e];
    __syncthreads();

    int per = (N + gridDim.x - 1) / gridDim.x;
    per = (per + 3) & ~3;
    const int base = blockIdx.x * per;
    int end = base + per; if (end > N) end = N;
    if (end <= base) return;
    const int end4 = base + ((end - base) & ~3);

    const int4* sp4 = (const int4*)sp;
    float4* o0 = (float4*)(out + (size_t)(g * NGB + 0) * N);
    float4* o1 = (float4*)(out + (size_t)(g * NGB + 1) * N);
    float4* o2 = (float4*)(out + (size_t)(g * NGB + 2) * N);
    float4* o3 = (float4*)(out + (size_t)(g * NGB + 3) * N);

    for (int rep = 0; rep < BCAST_REP; ++rep) {
        for (int q = (base >> 2) + (int)threadIdx.x; q < (end4 >> 2); q += BCAST_THREADS) {
            int4 s4 = sp4[q];
            float4 a = tbl[s4.x];
            float4 b = tbl[s4.y];
            float4 c = tbl[s4.z];
            float4 d = tbl[s4.w];
            o0[q] = make_float4(a.x, b.x, c.x, d.x);
            o1[q] = make_float4(a.y, b.y, c.y, d.y);
            o2[q] = make_float4(a.z, b.z, c.z, d.z);
            o3[q] = make_float4(a.w, b.w, c.w, d.w);
        }
        // scalar tail (empty for N=1M)
        for (int p = end4 + (int)threadIdx.x; p < end; p += BCAST_THREADS) {
            float4 m = tbl[sp[p]];
            out[(size_t)(g * NGB + 0) * N + p] = m.x;
            out[(size_t)(g * NGB + 1) * N + p] = m.y;
            out[(size_t)(g * NGB + 2) * N + p] = m.z;
            out[(size_t)(g * NGB + 3) * N + p] = m.w;
        }
    }
}

extern "C" void kernel_launch(void* const* d_in, const int* in_sizes, int n_in,
                              void* d_out, int out_size, void* d_ws, size_t ws_size,
                              hipStream_t stream) {
    const float* x = (const float*)d_in[0];
    const int* sp = (const int*)d_in[1];
    const int N = in_sizes[1];            // 1048576
    const int C = in_sizes[0] / N;        // 64
    float* out = (float*)d_out;
    float* ws = (float*)d_ws;

    const int S = NUM_SP;
    const int SC = S * C;                 // 131072

    // ws layout (floats): [counts: S][means: SC][partials(u64): chunks*NG_SUM*NUM_SP*2]
    float* counts = ws;
    float* means = ws + S;
    unsigned long long* partq = (unsigned long long*)(ws + S + SC);

    const size_t part_floats_per_chunk = (size_t)NG_SUM * NUM_SP * 2 * 2;  // 90112
    size_t ws_floats = ws_size / sizeof(float);
    size_t avail = (ws_floats > (size_t)(S + SC)) ? ws_floats - (size_t)(S + SC) : 0;
    int chunks = (int)(avail / part_floats_per_chunk);
    if (chunks > SUM_CHUNKS) chunks = SUM_CHUNKS;
    int use_partials = (chunks >= 32) ? 1 : 0;   // 21-bit field overflow bound
    int grid_chunks = use_partials ? chunks : SUM_CHUNKS;
    float scale = use_partials ? 1024.0f : 128.0f;   // 1024: margin for SUM_REP=2
    float bsr = 6.0f * scale + 0.5f;

    if (!use_partials) {
        // fallback accumulates atomically into one shared table: must be zeroed
        zero_kernel<<<64, 256, 0, stream>>>((float*)partq, (int)part_floats_per_chunk);
    }
    dim3 g2(grid_chunks, NG_SUM);
    sum_kernel<<<g2, SUM_THREADS, 0, stream>>>(x, sp, partq, N, grid_chunks,
                                               use_partials, scale, bsr);
    int rchunks = use_partials ? grid_chunks : 1;
    cnt_kernel<<<NUM_SP / 256, 256, 0, stream>>>(partq, counts, rchunks);
    mean_kernel<<<(SC + 255) / 256, 256, 0, stream>>>(partq, counts, means, SC,
                                                      rchunks, scale);
    dim3 gb(BCAST_CHUNKS, C / NGB);
    bcast_kernel<<<gb, BCAST_THREADS, 0, stream>>>(sp, (const float4*)means, out, N);
}